// Round 4
// baseline (189.162 us; speedup 1.0000x reference)
//
#include <hip/hip_runtime.h>

#define RESO 128

// ---------------------------------------------------------------------------
// One fused kernel.
//  - Each block recomputes the three 128-element prefix scans inline
//    (shuffle-based, ~100 cycles, hidden under the main memory traffic).
//    Tables staged in LDS: tab[0..2]=layers, tab[3..5]=a3, tab[6..8]=a6.
//  - Each thread then processes 4 sdf points and 4 render points with
//    float4/int4 loads and float4 stores (16 B/lane coalescing).
// Traffic: 134 MB read + 67 MB write => ~32 us roofline at 6.3 TB/s.
// ---------------------------------------------------------------------------
__global__ __launch_bounds__(256) void fused_kernel(
    const float* __restrict__ renderPts, const int* __restrict__ renderIdx,
    const float* __restrict__ sdfPts,    const int* __restrict__ sdfIdx,
    const float* __restrict__ xL, const float* __restrict__ yL,
    const float* __restrict__ zL, const float* __restrict__ off,
    float* __restrict__ sdfOut, float* __restrict__ nrmOut, int N)
{
    __shared__ float tab[9][RESO];
    __shared__ float s_a3[RESO];
    __shared__ float s_tmp[4];

    const int tid  = threadIdx.x;
    const int lane = tid & 63;
    const int wave = tid >> 6;

    // ---- inline scans over the 3 layers (waves 0,1 active; uniform cond) ----
    for (int ax = 0; ax < 3; ++ax) {
        const float* L = (ax == 0) ? xL : (ax == 1) ? yL : zL;
        float li = 0.f, lim1 = 0.f, v = 0.f, w = 0.f, a3v = 0.f;
        if (tid < RESO) {
            li   = L[tid];
            lim1 = (tid > 0) ? L[tid - 1] : 0.f;
            v = (tid == 0) ? 0.f : 2.f * lim1 + 2.f * li;
            #pragma unroll
            for (int o = 1; o < 64; o <<= 1) {
                float u = __shfl_up(v, o, 64);
                if (lane >= o) v += u;
            }
            if (lane == 63) s_tmp[wave] = v;
        }
        __syncthreads();
        if (tid < RESO) {
            if (wave == 1) v += s_tmp[0];
            a3v = off[ax] + v;
            s_a3[tid] = a3v;
        }
        __syncthreads();
        if (tid < RESO) {
            const float a3m1 = (tid > 0) ? s_a3[tid - 1] : 0.f;
            w = (tid == 0) ? 0.f : 3.f * lim1 + li + 2.f * a3m1;
            #pragma unroll
            for (int o = 1; o < 64; o <<= 1) {
                float u = __shfl_up(w, o, 64);
                if (lane >= o) w += u;
            }
            if (lane == 63) s_tmp[2 + wave] = w;
        }
        __syncthreads();
        if (tid < RESO) {
            if (wave == 1) w += s_tmp[2];
            tab[ax][tid]     = li;
            tab[3 + ax][tid] = a3v;
            tab[6 + ax][tid] = w;
        }
        __syncthreads();
    }

    const float off3 = off[3];
    const int Ng = N >> 2;                       // full groups of 4 points
    const int t  = blockIdx.x * blockDim.x + tid;

    if (t < Ng) {
        // ---------------- sdf: 4 points ----------------
        const int4   sid = ((const int4*)sdfIdx)[t];
        const float4 sp0 = ((const float4*)sdfPts)[3 * t + 0];
        const float4 sp1 = ((const float4*)sdfPts)[3 * t + 1];
        const float4 sp2 = ((const float4*)sdfPts)[3 * t + 2];
        const float px[4] = {sp0.x, sp0.w, sp1.z, sp2.y};
        const float py[4] = {sp0.y, sp1.x, sp1.w, sp2.z};
        const float pz[4] = {sp0.z, sp1.y, sp2.x, sp2.w};
        const int  ids[4] = {sid.x, sid.y, sid.z, sid.w};

        float sv[4];
        #pragma unroll
        for (int k = 0; k < 4; ++k) {
            const int id = ids[k];
            const int iz = id & 127;
            const int iy = (id >> 7) & 127;
            const int ix = (id >> 14) & 127;
            const float a0 = tab[0][iz] * px[k];
            const float a1 = tab[1][iy] * py[k];
            const float a2 = tab[2][ix] * pz[k];
            const float a3 = tab[3][iz];
            const float a4 = tab[4][iy];
            const float a5 = tab[5][ix];
            const float a6 = off3 + tab[6][iz] + tab[7][iy] + tab[8][ix];
            const float num = (a0 + a3) * px[k] + (a1 + a4) * py[k] + (a2 + a5) * pz[k] + a6;
            const float dx = 2.f * a0 + a3;
            const float dy = 2.f * a1 + a4;
            const float dz = 2.f * a2 + a5;
            const float den = sqrtf(dx * dx + dy * dy + dz * dz);
            sv[k] = num / den * (1.0f / (float)RESO);   // /128 is exact
        }
        ((float4*)sdfOut)[t] = make_float4(sv[0], sv[1], sv[2], sv[3]);

        // ---------------- render: 4 points ----------------
        const int4   rid = ((const int4*)renderIdx)[t];
        const float4 rp0 = ((const float4*)renderPts)[3 * t + 0];
        const float4 rp1 = ((const float4*)renderPts)[3 * t + 1];
        const float4 rp2 = ((const float4*)renderPts)[3 * t + 2];
        const float rx[4] = {rp0.x, rp0.w, rp1.z, rp2.y};
        const float ry[4] = {rp0.y, rp1.x, rp1.w, rp2.z};
        const float rz[4] = {rp0.z, rp1.y, rp2.x, rp2.w};
        const int  jds[4] = {rid.x, rid.y, rid.z, rid.w};

        float nx[4], ny[4], nz[4];
        #pragma unroll
        for (int k = 0; k < 4; ++k) {
            const int id = jds[k];
            const int jz = id & 127;
            const int jy = (id >> 7) & 127;
            const int jx = (id >> 14) & 127;
            float x = 2.f * tab[0][jz] * rx[k] + tab[3][jz];
            float y = 2.f * tab[1][jy] * ry[k] + tab[4][jy];
            float z = 2.f * tab[2][jx] * rz[k] + tab[5][jx];
            const float nrm = sqrtf(x * x + y * y + z * z);
            const float inv = 1.0f / fmaxf(nrm, 1e-12f);
            nx[k] = x * inv; ny[k] = y * inv; nz[k] = z * inv;
        }
        float4* no = (float4*)nrmOut;
        no[3 * t + 0] = make_float4(nx[0], ny[0], nz[0], nx[1]);
        no[3 * t + 1] = make_float4(ny[1], nz[1], nx[2], ny[2]);
        no[3 * t + 2] = make_float4(nz[2], nx[3], ny[3], nz[3]);
    }

    // ---------------- tail (N not divisible by 4) ----------------
    const int rem = N & 3;
    if (rem && t == Ng) {
        for (int r = 0; r < rem; ++r) {
            const int i = 4 * Ng + r;
            {
                const int id = sdfIdx[i];
                const int iz = id & 127, iy = (id >> 7) & 127, ix = (id >> 14) & 127;
                const float px_ = sdfPts[3 * i], py_ = sdfPts[3 * i + 1], pz_ = sdfPts[3 * i + 2];
                const float a0 = tab[0][iz] * px_;
                const float a1 = tab[1][iy] * py_;
                const float a2 = tab[2][ix] * pz_;
                const float a3 = tab[3][iz], a4 = tab[4][iy], a5 = tab[5][ix];
                const float a6 = off3 + tab[6][iz] + tab[7][iy] + tab[8][ix];
                const float num = (a0 + a3) * px_ + (a1 + a4) * py_ + (a2 + a5) * pz_ + a6;
                const float dx = 2.f * a0 + a3, dy = 2.f * a1 + a4, dz = 2.f * a2 + a5;
                sdfOut[i] = num / sqrtf(dx * dx + dy * dy + dz * dz) * (1.0f / (float)RESO);
            }
            {
                const int id = renderIdx[i];
                const int jz = id & 127, jy = (id >> 7) & 127, jx = (id >> 14) & 127;
                const float rx_ = renderPts[3 * i], ry_ = renderPts[3 * i + 1], rz_ = renderPts[3 * i + 2];
                float x = 2.f * tab[0][jz] * rx_ + tab[3][jz];
                float y = 2.f * tab[1][jy] * ry_ + tab[4][jy];
                float z = 2.f * tab[2][jx] * rz_ + tab[5][jx];
                const float inv = 1.0f / fmaxf(sqrtf(x * x + y * y + z * z), 1e-12f);
                nrmOut[3 * i] = x * inv; nrmOut[3 * i + 1] = y * inv; nrmOut[3 * i + 2] = z * inv;
            }
        }
    }
}

// ---------------------------------------------------------------------------
// Inputs (setup_inputs order):
//  0 renderPointList (N*3 f32)   1 renderIndexList (N i32)
//  2 sdfPointList    (N*3 f32)   3 sdfIndexList    (N i32)
//  4 xLayer (128 f32) 5 yLayer (128 f32) 6 zLayer (128 f32) 7 offset (4 f32)
// Output: sdfList (N f32) ++ normalList (N*3 f32)
// ---------------------------------------------------------------------------
extern "C" void kernel_launch(void* const* d_in, const int* in_sizes, int n_in,
                              void* d_out, int out_size, void* d_ws, size_t ws_size,
                              hipStream_t stream)
{
    const float* renderPts = (const float*)d_in[0];
    const int*   renderIdx = (const int*)d_in[1];
    const float* sdfPts    = (const float*)d_in[2];
    const int*   sdfIdx    = (const int*)d_in[3];
    const float* xL        = (const float*)d_in[4];
    const float* yL        = (const float*)d_in[5];
    const float* zL        = (const float*)d_in[6];
    const float* off       = (const float*)d_in[7];

    float* out = (float*)d_out;
    const int N = in_sizes[1];

    const int Ng    = N >> 2;
    const int rem   = N & 3;
    const int total = Ng + (rem ? 1 : 0);
    int grid = (total + 255) / 256;
    if (grid < 1) grid = 1;

    fused_kernel<<<grid, 256, 0, stream>>>(renderPts, renderIdx, sdfPts, sdfIdx,
                                           xL, yL, zL, off, out, out + N, N);
}